// Round 1
// baseline (148.349 us; speedup 1.0000x reference)
//
#include <hip/hip_runtime.h>
#include <math.h>

#define EPSF     1.1920928955078125e-07f   // float32 eps
#define BYPASSF  0.9999998807907104f       // 1 - eps
#define CLAMPF   1e30f
#define GSTRIDE  1020                      // words per subtree gate slab (bank-skewed, 16B aligned)
#define NBATCH   32768

struct C2 { float r, i; };

__device__ __forceinline__ float fixv(float v) {
  if (v != v) return 0.0f;                       // nan -> 0
  return fminf(fmaxf(v, -CLAMPF), CLAMPF);       // +-inf and overflow -> +-CLAMP
}

__device__ __forceinline__ void softmax3_store(float a, float b, float c, float* out) {
  float m = fmaxf(a, fmaxf(b, c));
  float e0 = expf(a - m), e1 = expf(b - m), e2 = expf(c - m);
  float s = (e0 + e1) + e2;
  out[0] = e0 / s; out[1] = e1 / s; out[2] = e2 / s;
}

__device__ __forceinline__ void softmax4_store(const float* __restrict__ in, float* out) {
  float a = in[0], b = in[1], c = in[2], d = in[3];
  float m = fmaxf(fmaxf(a, b), fmaxf(c, d));
  float e0 = expf(a - m), e1 = expf(b - m), e2 = expf(c - m), e3 = expf(d - m);
  float s = ((e0 + e1) + e2) + e3;
  out[0] = e0 / s; out[1] = e1 / s; out[2] = e2 / s; out[3] = e3 / s;
}

// _blend from the reference: ps = (p_term, p_x0, p_x1, p_child)
__device__ __forceinline__ C2 blendf(float4 ps, C2 child, float x0, float x1) {
  bool mc   = ps.w > EPSF;
  float pcs = mc ? ps.w    : 0.0f;
  float scr = mc ? child.r : 0.0f;
  float sci = mc ? child.i : 0.0f;
  float var = fmaf(ps.z, x1, ps.y * x0);
  float br  = fmaf(pcs, scr, ps.x) + var;   // p_term*1 + p_child*cr + var
  float bi  = pcs * sci;                    // imag: only child contributes (x_i == 0)
  // bypass chain, last one wins (term, then v0, then v1)
  bool bt = ps.x > BYPASSF, b0 = ps.y > BYPASSF, b1 = ps.z > BYPASSF;
  br = bt ? 1.0f : br;  bi = bt ? 0.0f : bi;
  br = b0 ? x0   : br;  bi = b0 ? 0.0f : bi;
  br = b1 ? x1   : br;  bi = b1 ? 0.0f : bi;
  C2 o; o.r = br; o.i = bi; return o;
}

// clamp(cexp(blend(gl, L)) - clog(blend(gr, R)))
__device__ __forceinline__ C2 combine2(const float* g8, C2 L, C2 R, float x0, float x1) {
  float4 gl = *(const float4*)(g8);
  float4 gr = *(const float4*)(g8 + 4);
  C2 lin = blendf(gl, L, x0, x1);
  C2 rin = blendf(gr, R, x0, x1);

  // complex exp, with scaled path for 88 < x < ~152 (FreeBSD/numpy __ldexp_cexpf region)
  float sy, cy;
  sincosf(lin.i, &sy, &cy);
  const float E64 = 6.235149080811617e27f;     // expf(64)
  bool big    = lin.r > 88.0f;
  float shift = big ? 64.0f : 0.0f;
  float scale = big ? E64   : 1.0f;
  float h    = expf(lin.r - shift);
  float er_r = (h * cy) * scale;
  float er_i = (h * sy) * scale;

  // complex log: hypot avoids overflow/underflow of r^2+i^2 (values reach 1e30)
  float lr = logf(hypotf(rin.r, rin.i));
  float li = atan2f(rin.i, rin.r);

  C2 o; o.r = fixv(er_r - lr); o.i = fixv(er_i - li);
  return o;
}

__global__ __launch_bounds__(256) void tree_kernel(
    const float* __restrict__ x,
    const float* __restrict__ leaf_logits,
    const float* __restrict__ gate_logits,
    float* __restrict__ out0, int cplx) {

  __shared__ __align__(16) float gds[8 * GSTRIDE];  // levels 1..7 gates, DFS order per subtree
  __shared__ __align__(16) float tds[7 * 8];        // gates 1016..1022 (levels 8..10)
  __shared__ __align__(16) float lw[3080];          // leaf softmax weights, +1 word skew / 128 rows

  const int tid = threadIdx.x;

  // ---- fill leaf weights (skewed: bank = (t + 3l) mod 32, distinct per subtree lane) ----
  for (int l = tid; l < 1024; l += 256) {
    float a = leaf_logits[l * 3 + 0];
    float b = leaf_logits[l * 3 + 1];
    float c = leaf_logits[l * 3 + 2];
    softmax3_store(a, b, c, &lw[l * 3 + (l >> 7)]);
  }
  // ---- fill gates for levels 1..7, reordered to per-subtree DFS-merge order ----
  for (int g = tid; g < 1016; g += 256) {
    int z  = 1024 - g;
    int k  = __clz(z - 1) - 21;                 // level 1..7
    int p  = g - (1024 - (2048 >> k));          // global pair index at level k
    int t  = p >> (7 - k);                      // owning subtree
    int pl = p & ((1 << (7 - k)) - 1);          // local pair index
    int L  = ((pl + 1) << k) - 1;               // last local leaf under this node
    int step = L - __popc(L) + (k - 1);         // DFS post-order merge step (0..126)
    float* dst = &gds[t * GSTRIDE + step * 8];
    softmax4_store(gate_logits + g * 8,     dst);
    softmax4_store(gate_logits + g * 8 + 4, dst + 4);
  }
  if (tid < 7) {
    int g = 1016 + tid;
    softmax4_store(gate_logits + g * 8,     &tds[tid * 8]);
    softmax4_store(gate_logits + g * 8 + 4, &tds[tid * 8 + 4]);
  }
  __syncthreads();

  const int gtid = blockIdx.x * 256 + tid;
  const int e  = gtid >> 3;        // batch element
  const int lt = tid & 7;          // subtree index within element
  const float2 xv = ((const float2*)x)[e];
  const float x0 = xv.x, x1 = xv.y;
  const float* gb = &gds[lt * GSTRIDE];

  C2 p0, p1, p2, p3, p4, p5, p6;   // pending left siblings, levels 1..7 (static regs)
  C2 res; res.r = 0.0f; res.i = 0.0f;
  int step = 0;

  #pragma unroll 1
  for (int l = 0; l < 128; ++l) {
    int leaf = (lt << 7) | l;
    int aw = leaf * 3 + (leaf >> 7);
    C2 cur;
    cur.r = fmaf(lw[aw + 2], x1, fmaf(lw[aw + 1], x0, lw[aw]));
    cur.i = 0.0f;
    // merge while current node is a right child (wave-uniform branches)
    if (!(l & 1))  { p0 = cur; continue; }
    cur = combine2(gb + step * 8, p0, cur, x0, x1); step++;
    if (!(l & 2))  { p1 = cur; continue; }
    cur = combine2(gb + step * 8, p1, cur, x0, x1); step++;
    if (!(l & 4))  { p2 = cur; continue; }
    cur = combine2(gb + step * 8, p2, cur, x0, x1); step++;
    if (!(l & 8))  { p3 = cur; continue; }
    cur = combine2(gb + step * 8, p3, cur, x0, x1); step++;
    if (!(l & 16)) { p4 = cur; continue; }
    cur = combine2(gb + step * 8, p4, cur, x0, x1); step++;
    if (!(l & 32)) { p5 = cur; continue; }
    cur = combine2(gb + step * 8, p5, cur, x0, x1); step++;
    if (!(l & 64)) { p6 = cur; continue; }
    cur = combine2(gb + step * 8, p6, cur, x0, x1); step++;
    res = cur;                                     // node (7, lt)
  }

  // ---- top 3 levels across the 8 lanes of this element ----
  C2 v = res;
  { // level 8: gate 1016 + (lt>>1)
    C2 o; o.r = __shfl_xor(v.r, 1); o.i = __shfl_xor(v.i, 1);
    C2 L = (lt & 1) ? o : v;
    C2 R = (lt & 1) ? v : o;
    v = combine2(&tds[(lt >> 1) * 8], L, R, x0, x1);
  }
  { // level 9: gate 1020 + (lt>>2)
    C2 o; o.r = __shfl_xor(v.r, 2); o.i = __shfl_xor(v.i, 2);
    C2 L = (lt & 2) ? o : v;
    C2 R = (lt & 2) ? v : o;
    v = combine2(&tds[(4 + (lt >> 2)) * 8], L, R, x0, x1);
  }
  { // level 10 (root): gate 1022
    C2 o; o.r = __shfl_xor(v.r, 4); o.i = __shfl_xor(v.i, 4);
    C2 L = (lt & 4) ? o : v;
    C2 R = (lt & 4) ? v : o;
    v = combine2(&tds[6 * 8], L, R, x0, x1);
  }

  if (lt == 0) {
    if (cplx) { out0[2 * e] = v.r; out0[2 * e + 1] = v.i; }
    else      { out0[e] = v.r; }
  }
}

// writes leaf_probs (1024x3) and gate_probs (1023x2x4) output chunks
__global__ __launch_bounds__(256) void probs_kernel(
    const float* __restrict__ leaf_logits,
    const float* __restrict__ gate_logits,
    float* __restrict__ out_leaf,
    float* __restrict__ out_gate) {
  int i = blockIdx.x * 256 + threadIdx.x;
  if (i < 1024) {
    softmax3_store(leaf_logits[i * 3], leaf_logits[i * 3 + 1], leaf_logits[i * 3 + 2],
                   &out_leaf[i * 3]);
  } else if (i < 1024 + 2046) {
    int j = i - 1024;
    softmax4_store(gate_logits + j * 4, &out_gate[j * 4]);
  }
}

extern "C" void kernel_launch(void* const* d_in, const int* in_sizes, int n_in,
                              void* d_out, int out_size, void* d_ws, size_t ws_size,
                              hipStream_t stream) {
  const float* x  = (const float*)d_in[0];   // (32768, 2)
  const float* ll = (const float*)d_in[1];   // (1024, 3)
  const float* gl = (const float*)d_in[2];   // (1023, 2, 4)
  float* out0 = (float*)d_out;

  // complex output chunk size: interleaved (re,im) = 65536 floats, or real-only = 32768
  int S = out_size - (3072 + 8184);
  int cplx = (S >= 2 * NBATCH) ? 1 : 0;
  float* out_leaf = out0 + S;
  float* out_gate = out_leaf + 3072;

  tree_kernel<<<NBATCH * 8 / 256, 256, 0, stream>>>(x, ll, gl, out0, cplx);
  probs_kernel<<<(1024 + 2046 + 255) / 256, 256, 0, stream>>>(ll, gl, out_leaf, out_gate);
}

// Round 2
// 87.705 us; speedup vs baseline: 1.6914x; 1.6914x over previous
//
#include <hip/hip_runtime.h>
#include <math.h>

#define EPSF     1.1920928955078125e-07f   // float32 eps
#define BYPASSF  0.9999998807907104f       // 1 - eps
#define CLAMPF   1e30f
#define GSTRIDE  1020                      // words per subtree gate slab
#define LSTRIDE  516                       // words per subtree leaf-weight slab (float4, skewed)
#define NBATCH   32768

struct C2 { float r, i; };

__device__ __forceinline__ float fixv(float v) {
  float c = fminf(fmaxf(v, -CLAMPF), CLAMPF);    // +-inf / overflow -> +-CLAMP
  return (v != v) ? 0.0f : c;                    // nan -> 0
}

__device__ __forceinline__ void softmax3_store(float a, float b, float c, float* out) {
  float m = fmaxf(a, fmaxf(b, c));
  float e0 = expf(a - m), e1 = expf(b - m), e2 = expf(c - m);
  float s = (e0 + e1) + e2;
  out[0] = e0 / s; out[1] = e1 / s; out[2] = e2 / s;
}

__device__ __forceinline__ void softmax4_store(const float* __restrict__ in, float* out) {
  float a = in[0], b = in[1], c = in[2], d = in[3];
  float m = fmaxf(fmaxf(a, b), fmaxf(c, d));
  float e0 = expf(a - m), e1 = expf(b - m), e2 = expf(c - m), e3 = expf(d - m);
  float s = ((e0 + e1) + e2) + e3;
  out[0] = e0 / s; out[1] = e1 / s; out[2] = e2 / s; out[3] = e3 / s;
}

// softmax + bypass/eps folding baked in: the runtime blend is then a pure FMA form.
// At most one prob can exceed 1-eps (probs sum to 1), so one-hot substitution is exact.
__device__ __forceinline__ void store_gate(const float* __restrict__ in, float* __restrict__ out) {
  float p[4];
  softmax4_store(in, p);
  if (p[3] <= EPSF) p[3] = 0.0f;                 // mask_c fold
  if (p[0] > BYPASSF)      { p[0]=1.f; p[1]=0.f; p[2]=0.f; p[3]=0.f; }
  else if (p[1] > BYPASSF) { p[0]=0.f; p[1]=1.f; p[2]=0.f; p[3]=0.f; }
  else if (p[2] > BYPASSF) { p[0]=0.f; p[1]=0.f; p[2]=1.f; p[3]=0.f; }
  out[0]=p[0]; out[1]=p[1]; out[2]=p[2]; out[3]=p[3];
}

// clamp(cexp(blend(gl, L)) - clog(blend(gr, R))) -- fast-transcendental version
__device__ __forceinline__ C2 combine2(const float* __restrict__ g8, C2 L, C2 R, float x0, float x1) {
  float4 gl = *(const float4*)(g8);
  float4 gr = *(const float4*)(g8 + 4);
  // folded blends: (p_term, p_x0, p_x1, p_child) with bypass/eps pre-applied
  float lr_ = fmaf(gl.w, L.r, gl.x) + fmaf(gl.z, x1, gl.y * x0);
  float li_ = gl.w * L.i;
  float rr_ = fmaf(gr.w, R.r, gr.x) + fmaf(gr.z, x1, gr.y * x0);
  float ri_ = gr.w * R.i;

  // ---- sincos(li_): Cody-Waite by 2pi, native HW sin/cos; precise fallback for huge args ----
  float sy, cy;
  {
    float y  = li_;
    float nf = rintf(y * 0.15915494309189535f);       // 1/(2pi)
    float yr = fmaf(nf, -6.2831855f, y);              // -fp32(2pi)
    yr = fmaf(nf, 1.7484556e-7f, yr);                 // +(fp32(2pi) - 2pi)
    sy = __sinf(yr); cy = __cosf(yr);
    if (fabsf(y) > 20000.0f) { sy = sinf(y); cy = cosf(y); }  // rare, exec-masked
  }

  // ---- exp(lr_) in scaled form: e^x = 2^n * e^r, ldexp handles ldexp_cexpf region + over/underflow ----
  float xe  = fminf(fmaxf(lr_, -200.0f), 200.0f);
  float nfe = rintf(xe * 1.4426950408889634f);        // log2(e)
  float re  = fmaf(nfe, -0.69314718246f, xe);         // -fp32(ln2)
  re = fmaf(nfe, 1.9046542e-9f, re);                  // -(ln2 - fp32(ln2))
  float eh  = exp2f(re * 1.4426950408889634f);        // e^r, r in [-ln2/2, ln2/2]
  int   ne  = (int)nfe;
  float er  = ldexpf(eh * cy, ne);
  float ei  = ldexpf(eh * sy, ne);

  // ---- clog(rr_ + i*ri_): shared s = min/max for both log-hypot and atan2 ----
  float ax = fabsf(rr_), ay = fabsf(ri_);
  float mx = fmaxf(ax, ay), mn = fminf(ax, ay);
  float s  = (mx == 0.0f) ? 0.0f : mn * __builtin_amdgcn_rcpf(mx);
  // log|z| = ln2 * (log2(mx) + 0.5*log2(1+s^2))  -- overflow-free at 1e30
  float lr = 0.69314718056f * fmaf(0.5f, __log2f(fmaf(s, s, 1.0f)), __log2f(mx));
  // atan2 via odd minimax poly on s in [0,1] (Sleef u35 coefficients)
  float z = s * s;
  float u =              0.00282363896f;
  u = fmaf(u, z, -0.0159569028f);
  u = fmaf(u, z,  0.0425049886f);
  u = fmaf(u, z, -0.0748900920f);
  u = fmaf(u, z,  0.1063479334f);
  u = fmaf(u, z, -0.1420273631f);
  u = fmaf(u, z,  0.1999269574f);
  u = fmaf(u, z, -0.3333310186f);
  float at = fmaf(s * z, u, s);
  at = (ay > ax)    ? (1.5707963705f - at) : at;
  at = (rr_ < 0.0f) ? (3.14159274f  - at) : at;
  float li = copysignf(at, ri_);

  C2 o; o.r = fixv(er - lr); o.i = fixv(ei - li);
  return o;
}

__global__ __launch_bounds__(256) void tree_kernel(
    const float* __restrict__ x,
    const float* __restrict__ leaf_logits,
    const float* __restrict__ gate_logits,
    float* __restrict__ out0, int cplx) {

  __shared__ __align__(16) float gds[8 * GSTRIDE];  // levels 1..7 gates, DFS order per subtree
  __shared__ __align__(16) float tds[7 * 8];        // gates 1016..1022 (levels 8..10)
  __shared__ __align__(16) float lw[8 * LSTRIDE];   // leaf weights as float4, bank-skewed per subtree

  const int tid = threadIdx.x;

  // ---- leaf weights: float4 {w0,w1,w2,0} at [ (l>>7)*516 + (l&127)*4 ] (banks 4t+4l, distinct per t) ----
  for (int l = tid; l < 1024; l += 256) {
    float p[3];
    softmax3_store(leaf_logits[l * 3], leaf_logits[l * 3 + 1], leaf_logits[l * 3 + 2], p);
    float4* dst = (float4*)&lw[(l >> 7) * LSTRIDE + (l & 127) * 4];
    *dst = make_float4(p[0], p[1], p[2], 0.0f);
  }
  // ---- gates for levels 1..7, reordered to per-subtree DFS-merge order, bypass-folded ----
  for (int g = tid; g < 1016; g += 256) {
    int z  = 1024 - g;
    int k  = __clz(z - 1) - 21;                 // level 1..7
    int p  = g - (1024 - (2048 >> k));          // global pair index at level k
    int t  = p >> (7 - k);                      // owning subtree
    int pl = p & ((1 << (7 - k)) - 1);          // local pair index
    int L  = ((pl + 1) << k) - 1;               // last local leaf under this node
    int step = L - __popc(L) + (k - 1);         // DFS post-order merge step (0..126)
    float* dst = &gds[t * GSTRIDE + step * 8];
    store_gate(gate_logits + g * 8,     dst);
    store_gate(gate_logits + g * 8 + 4, dst + 4);
  }
  if (tid < 7) {
    int g = 1016 + tid;
    store_gate(gate_logits + g * 8,     &tds[tid * 8]);
    store_gate(gate_logits + g * 8 + 4, &tds[tid * 8 + 4]);
  }
  __syncthreads();

  const int gtid = blockIdx.x * 256 + tid;
  const int e  = gtid >> 3;        // batch element
  const int lt = tid & 7;          // subtree index within element
  const float2 xv = ((const float2*)x)[e];
  const float x0 = xv.x, x1 = xv.y;
  const float* gb = &gds[lt * GSTRIDE];
  const float* lb = &lw[lt * LSTRIDE];

  C2 p1, p2, p3, p4, p5, p6;       // pending left siblings, levels 2..7 (static regs)
  C2 res; res.r = 0.0f; res.i = 0.0f;
  int step = 0;

  #pragma unroll 2
  for (int h = 0; h < 64; ++h) {   // one level-1 combine per iteration
    float4 w0 = *(const float4*)&lb[(2 * h) * 4];
    float4 w1 = *(const float4*)&lb[(2 * h + 1) * 4];
    C2 a, b;
    a.r = fmaf(w0.z, x1, fmaf(w0.y, x0, w0.x)); a.i = 0.0f;
    b.r = fmaf(w1.z, x1, fmaf(w1.y, x0, w1.x)); b.i = 0.0f;
    C2 cur = combine2(gb + step * 8, a, b, x0, x1); step++;
    if (!(h & 1))  { p1 = cur; continue; }
    cur = combine2(gb + step * 8, p1, cur, x0, x1); step++;
    if (!(h & 2))  { p2 = cur; continue; }
    cur = combine2(gb + step * 8, p2, cur, x0, x1); step++;
    if (!(h & 4))  { p3 = cur; continue; }
    cur = combine2(gb + step * 8, p3, cur, x0, x1); step++;
    if (!(h & 8))  { p4 = cur; continue; }
    cur = combine2(gb + step * 8, p4, cur, x0, x1); step++;
    if (!(h & 16)) { p5 = cur; continue; }
    cur = combine2(gb + step * 8, p5, cur, x0, x1); step++;
    if (!(h & 32)) { p6 = cur; continue; }
    cur = combine2(gb + step * 8, p6, cur, x0, x1); step++;
    res = cur;                                     // node (7, lt)
  }

  // ---- top 3 levels across the 8 lanes of this element ----
  C2 v = res;
  { // level 8: gate 1016 + (lt>>1)
    C2 o; o.r = __shfl_xor(v.r, 1); o.i = __shfl_xor(v.i, 1);
    C2 L = (lt & 1) ? o : v;
    C2 R = (lt & 1) ? v : o;
    v = combine2(&tds[(lt >> 1) * 8], L, R, x0, x1);
  }
  { // level 9: gate 1020 + (lt>>2)
    C2 o; o.r = __shfl_xor(v.r, 2); o.i = __shfl_xor(v.i, 2);
    C2 L = (lt & 2) ? o : v;
    C2 R = (lt & 2) ? v : o;
    v = combine2(&tds[(4 + (lt >> 2)) * 8], L, R, x0, x1);
  }
  { // level 10 (root): gate 1022
    C2 o; o.r = __shfl_xor(v.r, 4); o.i = __shfl_xor(v.i, 4);
    C2 L = (lt & 4) ? o : v;
    C2 R = (lt & 4) ? v : o;
    v = combine2(&tds[6 * 8], L, R, x0, x1);
  }

  if (lt == 0) {
    if (cplx) { out0[2 * e] = v.r; out0[2 * e + 1] = v.i; }
    else      { out0[e] = v.r; }
  }
}

// writes leaf_probs (1024x3) and gate_probs (1023x2x4) output chunks (raw softmax, no folding)
__global__ __launch_bounds__(256) void probs_kernel(
    const float* __restrict__ leaf_logits,
    const float* __restrict__ gate_logits,
    float* __restrict__ out_leaf,
    float* __restrict__ out_gate) {
  int i = blockIdx.x * 256 + threadIdx.x;
  if (i < 1024) {
    softmax3_store(leaf_logits[i * 3], leaf_logits[i * 3 + 1], leaf_logits[i * 3 + 2],
                   &out_leaf[i * 3]);
  } else if (i < 1024 + 2046) {
    int j = i - 1024;
    softmax4_store(gate_logits + j * 4, &out_gate[j * 4]);
  }
}

extern "C" void kernel_launch(void* const* d_in, const int* in_sizes, int n_in,
                              void* d_out, int out_size, void* d_ws, size_t ws_size,
                              hipStream_t stream) {
  const float* x  = (const float*)d_in[0];   // (32768, 2)
  const float* ll = (const float*)d_in[1];   // (1024, 3)
  const float* gl = (const float*)d_in[2];   // (1023, 2, 4)
  float* out0 = (float*)d_out;

  int S = out_size - (3072 + 8184);          // complex chunk: 2*32768 interleaved or 32768 real
  int cplx = (S >= 2 * NBATCH) ? 1 : 0;
  float* out_leaf = out0 + S;
  float* out_gate = out_leaf + 3072;

  tree_kernel<<<NBATCH * 8 / 256, 256, 0, stream>>>(x, ll, gl, out0, cplx);
  probs_kernel<<<(1024 + 2046 + 255) / 256, 256, 0, stream>>>(ll, gl, out_leaf, out_gate);
}

// Round 3
// 57.784 us; speedup vs baseline: 2.5673x; 1.5178x over previous
//
#include <hip/hip_runtime.h>
#include <math.h>

#define EPSF     1.1920928955078125e-07f   // float32 eps
#define BYPASSF  0.9999998807907104f       // 1 - eps
#define CLAMPF   1e30f
#define GSTRIDE  1020                      // words per subtree gate slab
#define LSTRIDE  516                       // words per subtree leaf-weight slab (float4, skewed)
#define NBATCH   32768

// split constants
#define INV2PI_HI 0.15915493667125701904f  // fp32(1/2pi)
#define INV2PI_LO 6.42063831e-9f           // 1/2pi - hi
#define L2E_HI    1.44269502162933349609f  // fp32(log2 e)
#define L2E_LO    1.92596299e-8f           // log2e - hi
#define LN2F      0.69314718055994530942f
#define PI_F      3.14159274101257324219f  // fp32 pi
#define PIO2_F    1.57079637050628662109f

struct C2 { float r, i; };

__device__ __forceinline__ float fixv(float v) {
  float c = fminf(fmaxf(v, -CLAMPF), CLAMPF);    // +-inf / overflow -> +-CLAMP
  return (v != v) ? 0.0f : c;                    // nan -> 0
}

// precise sincos for |y| > 20000 (rare; keep out of the hot loop's I-footprint)
__device__ __attribute__((noinline)) float2 slow_sincos(float y) {
  return make_float2(sinf(y), cosf(y));
}

__device__ __forceinline__ void softmax3_store(float a, float b, float c, float* out) {
  float m = fmaxf(a, fmaxf(b, c));
  float e0 = expf(a - m), e1 = expf(b - m), e2 = expf(c - m);
  float s = (e0 + e1) + e2;
  out[0] = e0 / s; out[1] = e1 / s; out[2] = e2 / s;
}

__device__ __forceinline__ void softmax4_store(const float* __restrict__ in, float* out) {
  float a = in[0], b = in[1], c = in[2], d = in[3];
  float m = fmaxf(fmaxf(a, b), fmaxf(c, d));
  float e0 = expf(a - m), e1 = expf(b - m), e2 = expf(c - m), e3 = expf(d - m);
  float s = ((e0 + e1) + e2) + e3;
  out[0] = e0 / s; out[1] = e1 / s; out[2] = e2 / s; out[3] = e3 / s;
}

// softmax + bypass/eps folding baked in (one-hot substitution is exact: probs sum to 1,
// so at most one can exceed 1-eps). Runtime blend is then a pure FMA form.
__device__ __forceinline__ void store_gate(const float* __restrict__ in, float* __restrict__ out) {
  float p[4];
  softmax4_store(in, p);
  if (p[3] <= EPSF) p[3] = 0.0f;                 // mask_c fold
  if (p[0] > BYPASSF)      { p[0]=1.f; p[1]=0.f; p[2]=0.f; p[3]=0.f; }
  else if (p[1] > BYPASSF) { p[0]=0.f; p[1]=1.f; p[2]=0.f; p[3]=0.f; }
  else if (p[2] > BYPASSF) { p[0]=0.f; p[1]=0.f; p[2]=1.f; p[3]=0.f; }
  out[0]=p[0]; out[1]=p[1]; out[2]=p[2]; out[3]=p[3];
}

// exp(x) = 2^n * 2^f via split log2e; returns eh=2^f and n (x pre-clamped to +-200)
__device__ __forceinline__ float exp_core(float xe, int* n_out) {
  float nf = rintf(xe * 1.4426950408889634f);
  float f  = fmaf(xe, L2E_HI, -nf);
  f        = fmaf(xe, L2E_LO, f);
  *n_out   = (int)nf;
  return __builtin_amdgcn_exp2f(f);
}

// clamp(cexp(blend(gl, L)) - clog(blend(gr, R))) -- general complex path
__device__ __forceinline__ C2 combine2(const float* __restrict__ g8, C2 L, C2 R, float x0, float x1) {
  float4 gl = *(const float4*)(g8);
  float4 gr = *(const float4*)(g8 + 4);
  // folded blends: (p_term, p_x0, p_x1, p_child) with bypass/eps pre-applied
  float lr_ = fmaf(gl.w, L.r, gl.x) + fmaf(gl.z, x1, gl.y * x0);
  float li_ = gl.w * L.i;
  float rr_ = fmaf(gr.w, R.r, gr.x) + fmaf(gr.z, x1, gr.y * x0);
  float ri_ = gr.w * R.i;

  // ---- sincos(li_) via revolution-domain Cody-Waite feeding HW v_sin/v_cos ----
  float sy, cy;
  {
    float nf = rintf(li_ * 0.15915494309189535f);
    float rv = fmaf(li_, INV2PI_HI, -nf);
    rv       = fmaf(li_, INV2PI_LO, rv);
    sy = __builtin_amdgcn_sinf(rv);               // sin(2pi * rv)
    cy = __builtin_amdgcn_cosf(rv);
    if (fabsf(li_) > 20000.0f) { float2 sc = slow_sincos(li_); sy = sc.x; cy = sc.y; }
  }

  // ---- exp(lr_) scaled: handles ldexp_cexpf region and over/underflow ----
  float xe = fminf(fmaxf(lr_, -200.0f), 200.0f);
  int ne;
  float eh = exp_core(xe, &ne);
  float er = __builtin_amdgcn_ldexpf(eh * cy, ne);
  float ei = __builtin_amdgcn_ldexpf(eh * sy, ne);

  // ---- clog(rr_ + i*ri_): shared s = min/max for log-hypot and atan2 ----
  float ax = fabsf(rr_), ay = fabsf(ri_);
  float mx = fmaxf(ax, ay), mn = fminf(ax, ay);
  float s  = (mx == 0.0f) ? 0.0f : mn * __builtin_amdgcn_rcpf(mx);
  float z  = s * s;
  // log|z| = ln2 * (log2(mx) + 0.5*log2(1+s^2)) -- overflow-free at 1e30
  float lr = LN2F * fmaf(0.5f, __builtin_amdgcn_logf(z + 1.0f), __builtin_amdgcn_logf(mx));
  // atan via odd minimax poly on s in [0,1] (Sleef u35)
  float u =              0.00282363896f;
  u = fmaf(u, z, -0.0159569028f);
  u = fmaf(u, z,  0.0425049886f);
  u = fmaf(u, z, -0.0748900920f);
  u = fmaf(u, z,  0.1063479334f);
  u = fmaf(u, z, -0.1420273631f);
  u = fmaf(u, z,  0.1999269574f);
  u = fmaf(u, z, -0.3333310186f);
  float at = fmaf(s * z, u, s);
  at = (ay > ax)    ? (PIO2_F - at) : at;
  at = (rr_ < 0.0f) ? (PI_F   - at) : at;
  float li = copysignf(at, ri_);

  C2 o; o.r = fixv(er - lr); o.i = fixv(ei - li);
  return o;
}

// level-1 specialization: both children are real leaves (imag inputs exactly 0)
__device__ __forceinline__ C2 combine_l1(const float* __restrict__ g8, float Lr, float Rr,
                                         float x0, float x1) {
  float4 gl = *(const float4*)(g8);
  float4 gr = *(const float4*)(g8 + 4);
  float lr_ = fmaf(gl.w, Lr, gl.x) + fmaf(gl.z, x1, gl.y * x0);
  float rr_ = fmaf(gr.w, Rr, gr.x) + fmaf(gr.z, x1, gr.y * x0);

  float xe = fminf(fmaxf(lr_, -200.0f), 200.0f);
  int ne;
  float eh = exp_core(xe, &ne);
  float er = __builtin_amdgcn_ldexpf(eh, ne);     // cy=1, sy=0

  float lr = LN2F * __builtin_amdgcn_logf(fabsf(rr_));  // log|rr_| (log2(0) = -inf ok)
  C2 o;
  o.r = fminf(fmaxf(er - lr, -CLAMPF), CLAMPF);   // NaN impossible here
  o.i = (rr_ < 0.0f) ? -PI_F : 0.0f;              // 0 - atan2(0, rr_)
  return o;
}

__global__ __launch_bounds__(512) void tree_kernel(
    const float* __restrict__ x,
    const float* __restrict__ leaf_logits,
    const float* __restrict__ gate_logits,
    float* __restrict__ out0, int cplx) {

  __shared__ __align__(16) float gds[8 * GSTRIDE];  // levels 1..7 gates, DFS order per subtree
  __shared__ __align__(16) float tds[7 * 8];        // gates 1016..1022 (levels 8..10)
  __shared__ __align__(16) float lw[8 * LSTRIDE];   // leaf weights as float4, bank-skewed per subtree

  const int tid = threadIdx.x;

  // ---- leaf weights: float4 {w0,w1,w2,0} at [(l>>7)*516 + (l&127)*4] ----
  for (int l = tid; l < 1024; l += 512) {
    float p[3];
    softmax3_store(leaf_logits[l * 3], leaf_logits[l * 3 + 1], leaf_logits[l * 3 + 2], p);
    float4* dst = (float4*)&lw[(l >> 7) * LSTRIDE + (l & 127) * 4];
    *dst = make_float4(p[0], p[1], p[2], 0.0f);
  }
  // ---- gates for levels 1..7, per-subtree DFS-merge order, bypass-folded ----
  for (int g = tid; g < 1016; g += 512) {
    int z  = 1024 - g;
    int k  = __clz(z - 1) - 21;                 // level 1..7
    int p  = g - (1024 - (2048 >> k));          // global pair index at level k
    int t  = p >> (7 - k);                      // owning subtree
    int pl = p & ((1 << (7 - k)) - 1);          // local pair index
    int L  = ((pl + 1) << k) - 1;               // last local leaf under this node
    int step = L - __popc(L) + (k - 1);         // DFS post-order merge step (0..126)
    float* dst = &gds[t * GSTRIDE + step * 8];
    store_gate(gate_logits + g * 8,     dst);
    store_gate(gate_logits + g * 8 + 4, dst + 4);
  }
  if (tid < 7) {
    int g = 1016 + tid;
    store_gate(gate_logits + g * 8,     &tds[tid * 8]);
    store_gate(gate_logits + g * 8 + 4, &tds[tid * 8 + 4]);
  }
  __syncthreads();

  const int gtid = blockIdx.x * 512 + tid;
  const int e  = gtid >> 3;        // batch element
  const int lt = tid & 7;          // subtree index within element
  const float2 xv = ((const float2*)x)[e];
  const float x0 = xv.x, x1 = xv.y;
  const float* gb = &gds[lt * GSTRIDE];
  const float* lb = &lw[lt * LSTRIDE];

  C2 p1, p2, p3, p4, p5, p6;       // pending left siblings, levels 2..7 (static regs)
  C2 res; res.r = 0.0f; res.i = 0.0f;
  int step = 0;

  #pragma unroll 2
  for (int h = 0; h < 64; ++h) {   // one level-1 combine per iteration
    float4 w0 = *(const float4*)&lb[(2 * h) * 4];
    float4 w1 = *(const float4*)&lb[(2 * h + 1) * 4];
    float a = fmaf(w0.z, x1, fmaf(w0.y, x0, w0.x));
    float b = fmaf(w1.z, x1, fmaf(w1.y, x0, w1.x));
    C2 cur = combine_l1(gb + step * 8, a, b, x0, x1); step++;
    if (!(h & 1))  { p1 = cur; continue; }
    cur = combine2(gb + step * 8, p1, cur, x0, x1); step++;
    if (!(h & 2))  { p2 = cur; continue; }
    cur = combine2(gb + step * 8, p2, cur, x0, x1); step++;
    if (!(h & 4))  { p3 = cur; continue; }
    cur = combine2(gb + step * 8, p3, cur, x0, x1); step++;
    if (!(h & 8))  { p4 = cur; continue; }
    cur = combine2(gb + step * 8, p4, cur, x0, x1); step++;
    if (!(h & 16)) { p5 = cur; continue; }
    cur = combine2(gb + step * 8, p5, cur, x0, x1); step++;
    if (!(h & 32)) { p6 = cur; continue; }
    cur = combine2(gb + step * 8, p6, cur, x0, x1); step++;
    res = cur;                                     // node (7, lt)
  }

  // ---- top 3 levels across the 8 lanes of this element ----
  C2 v = res;
  { // level 8: gate 1016 + (lt>>1)
    C2 o; o.r = __shfl_xor(v.r, 1); o.i = __shfl_xor(v.i, 1);
    C2 L = (lt & 1) ? o : v;
    C2 R = (lt & 1) ? v : o;
    v = combine2(&tds[(lt >> 1) * 8], L, R, x0, x1);
  }
  { // level 9: gate 1020 + (lt>>2)
    C2 o; o.r = __shfl_xor(v.r, 2); o.i = __shfl_xor(v.i, 2);
    C2 L = (lt & 2) ? o : v;
    C2 R = (lt & 2) ? v : o;
    v = combine2(&tds[(4 + (lt >> 2)) * 8], L, R, x0, x1);
  }
  { // level 10 (root): gate 1022
    C2 o; o.r = __shfl_xor(v.r, 4); o.i = __shfl_xor(v.i, 4);
    C2 L = (lt & 4) ? o : v;
    C2 R = (lt & 4) ? v : o;
    v = combine2(&tds[6 * 8], L, R, x0, x1);
  }

  if (lt == 0) {
    if (cplx) { out0[2 * e] = v.r; out0[2 * e + 1] = v.i; }
    else      { out0[e] = v.r; }
  }
}

// writes leaf_probs (1024x3) and gate_probs (1023x2x4) output chunks (raw softmax, no folding)
__global__ __launch_bounds__(256) void probs_kernel(
    const float* __restrict__ leaf_logits,
    const float* __restrict__ gate_logits,
    float* __restrict__ out_leaf,
    float* __restrict__ out_gate) {
  int i = blockIdx.x * 256 + threadIdx.x;
  if (i < 1024) {
    softmax3_store(leaf_logits[i * 3], leaf_logits[i * 3 + 1], leaf_logits[i * 3 + 2],
                   &out_leaf[i * 3]);
  } else if (i < 1024 + 2046) {
    int j = i - 1024;
    softmax4_store(gate_logits + j * 4, &out_gate[j * 4]);
  }
}

extern "C" void kernel_launch(void* const* d_in, const int* in_sizes, int n_in,
                              void* d_out, int out_size, void* d_ws, size_t ws_size,
                              hipStream_t stream) {
  const float* x  = (const float*)d_in[0];   // (32768, 2)
  const float* ll = (const float*)d_in[1];   // (1024, 3)
  const float* gl = (const float*)d_in[2];   // (1023, 2, 4)
  float* out0 = (float*)d_out;

  int S = out_size - (3072 + 8184);          // complex chunk: 2*32768 interleaved or 32768 real
  int cplx = (S >= 2 * NBATCH) ? 1 : 0;
  float* out_leaf = out0 + S;
  float* out_gate = out_leaf + 3072;

  tree_kernel<<<512, 512, 0, stream>>>(x, ll, gl, out0, cplx);
  probs_kernel<<<(1024 + 2046 + 255) / 256, 256, 0, stream>>>(ll, gl, out_leaf, out_gate);
}